// Round 9
// baseline (201.152 us; speedup 1.0000x reference)
//
#include <hip/hip_runtime.h>

#define BATCH 8
#define SEQ   2048
#define EMB   1024
#define HD    64
#define HEADS 16
#define BS    (BATCH * SEQ)
#define LOG2E 1.4426950408889634f

typedef _Float16 half8 __attribute__((ext_vector_type(8)));
typedef _Float16 half4 __attribute__((ext_vector_type(4)));
typedef float    f32x4 __attribute__((ext_vector_type(4)));

__device__ __forceinline__ float fexp2(float x) {
#if __has_builtin(__builtin_amdgcn_exp2f)
    return __builtin_amdgcn_exp2f(x);
#else
    return exp2f(x);
#endif
}

__device__ __forceinline__ float frcp(float x) {
#if __has_builtin(__builtin_amdgcn_rcpf)
    return __builtin_amdgcn_rcpf(x);
#else
    return 1.0f / x;
#endif
}

// async global->LDS DMA: lane i deposits its element at lds_base + i*size.
// lds_base must be wave-uniform; gsrc is per-lane.
__device__ __forceinline__ void dma16(void* lds_base, const void* gsrc) {
    __builtin_amdgcn_global_load_lds(
        (const __attribute__((address_space(1))) unsigned int*)gsrc,
        (__attribute__((address_space(3))) unsigned int*)lds_base, 16, 0, 0);
}

// ---------------- W -> fp16 (Wq pre-scaled by log2e: scores in log2 domain)
__global__ __launch_bounds__(256) void wcvt_kernel(
    const float* __restrict__ Wq, const float* __restrict__ Wk,
    const float* __restrict__ Wv, _Float16* __restrict__ Wh)
{
    const int m = blockIdx.y;
    const float* src = (m == 0) ? Wq : (m == 1) ? Wk : Wv;
    const float scale = (m == 0) ? LOG2E : 1.0f;
    const int idx = (blockIdx.x * 256 + threadIdx.x) * 8;
    float4 f0 = *(const float4*)(src + idx);
    float4 f1 = *(const float4*)(src + idx + 4);
    half8 h;
    h[0] = (_Float16)(f0.x * scale); h[1] = (_Float16)(f0.y * scale);
    h[2] = (_Float16)(f0.z * scale); h[3] = (_Float16)(f0.w * scale);
    h[4] = (_Float16)(f1.x * scale); h[5] = (_Float16)(f1.y * scale);
    h[6] = (_Float16)(f1.z * scale); h[7] = (_Float16)(f1.w * scale);
    *(half8*)(Wh + (size_t)m * 65536 + idx) = h;
}

// ---------------- QKV projection: x via DMA, W DIRECT global->VGPR ----------
// 512 blocks x 512 thr (8 waves). Block = 32 rows, 12 ctiles; wave: strip=(w&1),
// grp=(w>>1) -> 3 ctiles. x staged by DMA (1 dma16/wave/chunk, 2x8KB dbuf,
// swizzled). W (L2-resident, 384KB) ping-pong prefetched into named wA/wB
// register sets one chunk ahead -> DMA path carries 64MB instead of 260MB.
__global__ __launch_bounds__(512) void qkv_kernel(
    const float* __restrict__ x, const _Float16* __restrict__ Wh,
    _Float16* __restrict__ qh, _Float16* __restrict__ kh, _Float16* __restrict__ vpt)
{
    __shared__ __align__(16) char arena[16384];  // x: 2 x 8KB
    const int t = threadIdx.x, lane = t & 63, wave = t >> 6;
    const int l15 = lane & 15, quad = lane >> 4;
    const int strip = wave & 1, grp = wave >> 1;   // grp in [0,4)
    const int row0 = blockIdx.x * 32;

    auto issueX = [&](int buf, int k0) {
        // 8 instrs total (1/wave): 4 rows x 16 swizzled 16B segs each
        const int row = wave * 4 + (lane >> 4);
        const int logi = (lane & 15) ^ (row & 15);
        dma16((float*)(arena + buf * 8192) + wave * 256,
              x + (size_t)(row0 + row) * EMB + k0 + logi * 4);
    };
    auto loadW = [&](int k0, half8 (&w)[3][2]) {
        #pragma unroll
        for (int j = 0; j < 3; ++j) {
            const int g = (grp * 3 + j) * 16 + l15;            // W row [0,192)
            const _Float16* wp = Wh + (size_t)(g >> 6) * 65536
                               + (size_t)(g & 63) * EMB + k0 + quad * 8;
            w[j][0] = *(const half8*)(wp);
            w[j][1] = *(const half8*)(wp + 32);
        }
    };

    f32x4 acc[3] = {};
    const int xrow = strip * 16 + l15;
    auto step = [&](int buf, const half8 (&w)[3][2]) {
        const float* xb = (const float*)(arena + buf * 8192);
        half8 a[2];
        #pragma unroll
        for (int kc = 0; kc < 2; ++kc) {
            const int s0 = kc * 8 + quad * 2;
            f32x4 u0 = *(const f32x4*)(xb + xrow * 64 + ((s0    ) ^ l15) * 4);
            f32x4 u1 = *(const f32x4*)(xb + xrow * 64 + ((s0 + 1) ^ l15) * 4);
            a[kc][0] = (_Float16)u0[0]; a[kc][1] = (_Float16)u0[1];
            a[kc][2] = (_Float16)u0[2]; a[kc][3] = (_Float16)u0[3];
            a[kc][4] = (_Float16)u1[0]; a[kc][5] = (_Float16)u1[1];
            a[kc][6] = (_Float16)u1[2]; a[kc][7] = (_Float16)u1[3];
        }
        #pragma unroll
        for (int j = 0; j < 3; ++j) {
            acc[j] = __builtin_amdgcn_mfma_f32_16x16x32_f16(a[0], w[j][0], acc[j], 0, 0, 0);
            acc[j] = __builtin_amdgcn_mfma_f32_16x16x32_f16(a[1], w[j][1], acc[j], 0, 0, 0);
        }
    };

    half8 wA[3][2], wB[3][2];
    issueX(0, 0);
    loadW(0, wA);
    __syncthreads();
    for (int it = 0; it < 16; it += 2) {
        issueX(1, (it + 1) * 64);            // it+1 <= 15 always
        loadW((it + 1) * 64, wB);
        step(0, wA);
        __syncthreads();
        if (it + 2 < 16) { issueX(0, (it + 2) * 64); loadW((it + 2) * 64, wA); }
        step(1, wB);
        __syncthreads();
    }

    #pragma unroll
    for (int j = 0; j < 3; ++j) {
        const int c = grp * 3 + j, m = c >> 2, n = c & 3;
        if (m < 2) {
            _Float16* __restrict__ dst = (m == 0) ? qh : kh;
            #pragma unroll
            for (int r = 0; r < 4; ++r)
                dst[(size_t)(row0 + strip * 16 + quad * 4 + r) * HD + n * 16 + l15] =
                    (_Float16)acc[j][r];
        } else {
            const int rg = row0 + strip * 16 + quad * 4;
            const int b = rg >> 11, s = rg & 2047;
            half4 h;
            h[0] = (_Float16)acc[j][0]; h[1] = (_Float16)acc[j][1];
            h[2] = (_Float16)acc[j][2]; h[3] = (_Float16)acc[j][3];
            *(half4*)(vpt + ((size_t)b * HD + n * 16 + l15) * SEQ + s) = h;
        }
    }
}

// ---------------- Column-softmax partials (128-key blocks, query-quarters) --
// grid (16,8,4) x 256 thr (4 waves). Block = 128 keys (ka[8][2] A-frags in
// regs); z = query-quarter: 8 DMA'd chunks of 64 queries, double-buffered,
// swizzled; wave w -> queries w*16. 16 MFMA per 2-DMA chunk per wave.
// Writes RAW partial sums l_part[z][b][key].
__global__ __launch_bounds__(256) void stats_kernel(
    const _Float16* __restrict__ qh, const _Float16* __restrict__ kh,
    float* __restrict__ l_part)
{
    __shared__ __align__(16) char arena[16384];  // q: 2x8KB
    __shared__ float red[4][128];
    const int t = threadIdx.x, lane = t & 63, wave = t >> 6;
    const int l15 = lane & 15, quad = lane >> 4;
    const int b = blockIdx.y, c0 = blockIdx.x * 128, z = blockIdx.z;
    const int qbase = z * 512;

    half8 ka[8][2];
    #pragma unroll
    for (int kt = 0; kt < 8; ++kt) {
        const _Float16* kp = kh + ((size_t)b * SEQ + c0 + kt * 16 + l15) * HD + quad * 8;
        ka[kt][0] = *(const half8*)(kp);
        ka[kt][1] = *(const half8*)(kp + 32);
    }

    auto issue = [&](int buf, int q0) {
        #pragma unroll
        for (int jj = 0; jj < 2; ++jj) {
            const int j = wave * 2 + jj;
            const int qq = j * 8 + (lane >> 3);
            const int logi = (lane & 7) ^ (qq & 7);
            dma16((_Float16*)(arena + buf * 8192) + j * 512,
                  qh + ((size_t)b * SEQ + qbase + q0 + qq) * HD + logi * 8);
        }
    };

    issue(0, 0);
    __syncthreads();

    float csum[8][4] = {};
    const int qrow = wave * 16 + l15;
    for (int it = 0; it < 8; ++it) {
        const int buf = it & 1;
        if (it + 1 < 8) issue(buf ^ 1, (it + 1) * 64);
        const _Float16* qb = (const _Float16*)(arena + buf * 8192);
        half8 bq0 = *(const half8*)(qb + qrow * 64 + (((quad    ) ^ (l15 & 7)) * 8));
        half8 bq1 = *(const half8*)(qb + qrow * 64 + (((4 + quad) ^ (l15 & 7)) * 8));
        #pragma unroll
        for (int kt = 0; kt < 8; ++kt) {
            f32x4 s = {};
            s = __builtin_amdgcn_mfma_f32_16x16x32_f16(ka[kt][0], bq0, s, 0, 0, 0);
            s = __builtin_amdgcn_mfma_f32_16x16x32_f16(ka[kt][1], bq1, s, 0, 0, 0);
            #pragma unroll
            for (int r = 0; r < 4; ++r)
                csum[kt][r] += fexp2(s[r]);
        }
        __syncthreads();
    }
    #pragma unroll
    for (int kt = 0; kt < 8; ++kt)
        #pragma unroll
        for (int r = 0; r < 4; ++r) {
            csum[kt][r] += __shfl_xor(csum[kt][r], 1);
            csum[kt][r] += __shfl_xor(csum[kt][r], 2);
            csum[kt][r] += __shfl_xor(csum[kt][r], 4);
            csum[kt][r] += __shfl_xor(csum[kt][r], 8);
        }
    if (l15 == 0) {
        #pragma unroll
        for (int kt = 0; kt < 8; ++kt)
            #pragma unroll
            for (int r = 0; r < 4; ++r)
                red[wave][kt * 16 + quad * 4 + r] = csum[kt][r];
    }
    __syncthreads();
    if (t < 128)
        l_part[(size_t)z * BS + (size_t)b * SEQ + c0 + t] =
            red[0][t] + red[1][t] + red[2][t] + red[3][t];
}

// ---------------- opart[z] = P~ @ v (128-row blocks, 8 waves) --------------
// grid (16,8,2) x 512 thr (8 waves). Block = 128 q-rows; wave w owns rows
// w*16..+15 over ALL 64 staged keys per chunk (r7 per-wave body verbatim).
// z = key-half: 16 chunks of 64 keys, k/v DMA'd (2 dma16/wave/chunk),
// double-buffered, swizzled. K/V staged bytes halved vs r7 (64MB total).
// 1/l (sum of 4 query-quarter partials) preloaded into LDS. Wave-private P
// LDS round trip (stride 76). Compact f32 partial write; x16 in bcast.
__global__ __launch_bounds__(512) void out_kernel(
    const _Float16* __restrict__ qh, const _Float16* __restrict__ kh,
    const _Float16* __restrict__ vpt, const float* __restrict__ l_part,
    float* __restrict__ opart)
{
    __shared__ __align__(16) char arena[56320];
    // [0,16384)      kbuf [2][64][64] fp16
    // [16384,32768)  vbuf [2][64][64] fp16
    // [32768,52224)  ps   [8 waves][16][76] fp16
    // [52224,56320)  ls   [1024] f32 (1/l for this z key-half)
    const int t = threadIdx.x, lane = t & 63, wave = t >> 6;
    const int l15 = lane & 15, quad = lane >> 4;
    const int b = blockIdx.y, r0 = blockIdx.x * 128, z = blockIdx.z;
    const int kbase = z * 1024;

    half8 aq[2];
    {
        const _Float16* qp = qh + ((size_t)b * SEQ + r0 + wave * 16 + l15) * HD + quad * 8;
        aq[0] = *(const half8*)(qp);
        aq[1] = *(const half8*)(qp + 32);
    }

    // 1/l preload: sum the 4 query-quarter partials, reciprocal once
    const float* lp = l_part + (size_t)b * SEQ;   // quarter z' at +z'*BS
    float* ls = (float*)(arena + 52224);
    for (int i = t; i < 1024; i += 512) {
        const int kg = kbase + i;
        ls[i] = frcp((lp[kg] + lp[BS + kg]) + (lp[2 * BS + kg] + lp[3 * BS + kg]));
    }

    auto issue = [&](int buf, int c0) {
        #pragma unroll
        for (int jj = 0; jj < 2; ++jj) {
            if (wave < 4) {        // k: 8 instrs, 64 key-rows x 64B
                const int j = wave * 2 + jj;
                const int key = j * 8 + (lane >> 3);
                const int logi = (lane & 7) ^ (key & 7);
                dma16((_Float16*)(arena + buf * 8192) + j * 512,
                      kh + ((size_t)b * SEQ + c0 + key) * HD + logi * 8);
            } else {               // v: 8 instrs (vpt is [b][d][s])
                const int j = (wave - 4) * 2 + jj;
                const int d = j * 8 + (lane >> 3);
                const int logi = (lane & 7) ^ (d & 7);
                dma16((_Float16*)(arena + 16384 + buf * 8192) + j * 512,
                      vpt + ((size_t)b * HD + d) * SEQ + c0 + logi * 8);
            }
        }
    };

    issue(0, kbase);
    __syncthreads();

    _Float16* psb = (_Float16*)(arena + 32768) + wave * 1216;  // [16][76]
    f32x4 oacc[4] = {};
    for (int it = 0; it < 16; ++it) {
        const int buf = it & 1;
        if (it + 1 < 16) issue(buf ^ 1, kbase + (it + 1) * 64);
        const _Float16* kb = (const _Float16*)(arena + buf * 8192);
        const _Float16* vb = (const _Float16*)(arena + 16384 + buf * 8192);

        #pragma unroll
        for (int ct = 0; ct < 4; ++ct) {
            const int key = ct * 16 + l15;
            f32x4 s = {};
            half8 kf0 = *(const half8*)(kb + key * 64 + (((quad    ) ^ (l15 & 7)) * 8));
            half8 kf1 = *(const half8*)(kb + key * 64 + (((4 + quad) ^ (l15 & 7)) * 8));
            s = __builtin_amdgcn_mfma_f32_16x16x32_f16(aq[0], kf0, s, 0, 0, 0);
            s = __builtin_amdgcn_mfma_f32_16x16x32_f16(aq[1], kf1, s, 0, 0, 0);
            const float li = ls[it * 64 + key];
            #pragma unroll
            for (int r = 0; r < 4; ++r)
                psb[(quad * 4 + r) * 76 + ct * 16 + l15] =
                    (_Float16)(fexp2(s[r]) * li);
        }
        half8 paA = *(const half8*)(psb + l15 * 76 + quad * 8);        // keys 0..31
        half8 paB = *(const half8*)(psb + l15 * 76 + 32 + quad * 8);   // keys 32..63
        #pragma unroll
        for (int n = 0; n < 4; ++n) {
            const int d = n * 16 + l15;
            half8 vfA = *(const half8*)(vb + d * 64 + (((quad    ) ^ (l15 & 7)) * 8));
            half8 vfB = *(const half8*)(vb + d * 64 + (((4 + quad) ^ (l15 & 7)) * 8));
            oacc[n] = __builtin_amdgcn_mfma_f32_16x16x32_f16(paA, vfA, oacc[n], 0, 0, 0);
            oacc[n] = __builtin_amdgcn_mfma_f32_16x16x32_f16(paB, vfB, oacc[n], 0, 0, 0);
        }
        __syncthreads();
    }

    // compact write: wave-private 16x64 f32 tile -> opart[z]
    #pragma unroll
    for (int n = 0; n < 4; ++n)
        #pragma unroll
        for (int r = 0; r < 4; ++r) {
            const int row = r0 + wave * 16 + quad * 4 + r;
            opart[(size_t)z * ((size_t)BS * HD)
                  + ((size_t)b * SEQ + row) * HD + n * 16 + l15] = oacc[n][r];
        }
}

// ---------------- out[b,s,h*64+d] = opart[0][b,s,d] + opart[1][b,s,d] -----
// Pure-BW broadcast: one block per (b,s) row; 256 threads cover the 1024-f32
// output row with one float4 each. Reads 8 MiB, writes 64 MiB, coalesced.
__global__ __launch_bounds__(256) void bcast_kernel(
    const float* __restrict__ opart, float* __restrict__ out)
{
    const int row = blockIdx.x;          // [0, BS)
    const int t = threadIdx.x;
    const int d = (t * 4) & 63;          // source offset within the 64-f32 O row
    const float* o0 = opart + (size_t)row * HD + d;
    const float* o1 = o0 + (size_t)BS * HD;
    float4 a = *(const float4*)o0;
    float4 c = *(const float4*)o1;
    float4 s;
    s.x = a.x + c.x; s.y = a.y + c.y; s.z = a.z + c.z; s.w = a.w + c.w;
    *(float4*)(out + (size_t)row * (HD * HEADS) + t * 4) = s;
}

extern "C" void kernel_launch(void* const* d_in, const int* in_sizes, int n_in,
                              void* d_out, int out_size, void* d_ws, size_t ws_size,
                              hipStream_t stream)
{
    const float* x  = (const float*)d_in[0];
    const float* Wq = (const float*)d_in[1];
    const float* Wk = (const float*)d_in[2];
    const float* Wv = (const float*)d_in[3];
    float* out = (float*)d_out;

    const size_t N = (size_t)BATCH * SEQ * HD;   // 1,048,576
    _Float16* qh  = (_Float16*)d_ws;
    _Float16* kh  = qh + N;
    _Float16* vpt = kh + N;
    _Float16* Wh  = vpt + N;                     // 3*64*1024 halves
    float* l_part = (float*)(Wh + 196608);       // [4][B][S] f32 (256 KB)
    float* opart  = l_part + 4 * BS;             // [2][B][S][64] f32 (8 MiB)

    wcvt_kernel <<<dim3(32, 3),    256, 0, stream>>>(Wq, Wk, Wv, Wh);
    qkv_kernel  <<<dim3(512),      512, 0, stream>>>(x, Wh, qh, kh, vpt);
    stats_kernel<<<dim3(16, 8, 4), 256, 0, stream>>>(qh, kh, l_part);
    out_kernel  <<<dim3(16, 8, 2), 512, 0, stream>>>(qh, kh, vpt, l_part, opart);
    bcast_kernel<<<dim3(BS),       256, 0, stream>>>(opart, out);
}

// Round 10
// 180.772 us; speedup vs baseline: 1.1127x; 1.1127x over previous
//
#include <hip/hip_runtime.h>

#define BATCH 8
#define SEQ   2048
#define EMB   1024
#define HD    64
#define HEADS 16
#define BS    (BATCH * SEQ)
#define LOG2E 1.4426950408889634f

typedef _Float16 half8 __attribute__((ext_vector_type(8)));
typedef _Float16 half4 __attribute__((ext_vector_type(4)));
typedef float    f32x4 __attribute__((ext_vector_type(4)));

__device__ __forceinline__ float fexp2(float x) {
#if __has_builtin(__builtin_amdgcn_exp2f)
    return __builtin_amdgcn_exp2f(x);
#else
    return exp2f(x);
#endif
}

__device__ __forceinline__ float frcp(float x) {
#if __has_builtin(__builtin_amdgcn_rcpf)
    return __builtin_amdgcn_rcpf(x);
#else
    return 1.0f / x;
#endif
}

// async global->LDS DMA: lane i deposits its element at lds_base + i*size.
// lds_base must be wave-uniform; gsrc is per-lane.
__device__ __forceinline__ void dma16(void* lds_base, const void* gsrc) {
    __builtin_amdgcn_global_load_lds(
        (const __attribute__((address_space(1))) unsigned int*)gsrc,
        (__attribute__((address_space(3))) unsigned int*)lds_base, 16, 0, 0);
}

// ---------------- W -> fp16, PACKED in MFMA-fragment order ------------------
// Wq pre-scaled by log2e (scores in log2 domain). Packed layout:
// Wpk[tile=dd>>4][kchunk=k>>6][seg=(k&63)>>3][row16=dd&15][8], dd=m*64+d.
// A qkv fragment load (fixed tile,kchunk,seg) then reads 16 lanes x 16B
// CONTIGUOUS (256B) -> coalesced, unlike row-major W (2KB row stride).
__global__ __launch_bounds__(256) void wcvt_kernel(
    const float* __restrict__ Wq, const float* __restrict__ Wk,
    const float* __restrict__ Wv, _Float16* __restrict__ Wh)
{
    const int m = blockIdx.y;
    const float* src = (m == 0) ? Wq : (m == 1) ? Wk : Wv;
    const float scale = (m == 0) ? LOG2E : 1.0f;
    const int idx = (blockIdx.x * 256 + threadIdx.x) * 8;   // d*1024 + k, k%8==0
    float4 f0 = *(const float4*)(src + idx);
    float4 f1 = *(const float4*)(src + idx + 4);
    half8 h;
    h[0] = (_Float16)(f0.x * scale); h[1] = (_Float16)(f0.y * scale);
    h[2] = (_Float16)(f0.z * scale); h[3] = (_Float16)(f0.w * scale);
    h[4] = (_Float16)(f1.x * scale); h[5] = (_Float16)(f1.y * scale);
    h[6] = (_Float16)(f1.z * scale); h[7] = (_Float16)(f1.w * scale);
    const int d = idx >> 10, k = idx & 1023;
    const int dd = m * 64 + d;
    const size_t off = ((((size_t)(dd >> 4) * 16 + (k >> 6)) * 8
                         + ((k & 63) >> 3)) * 16 + (dd & 15)) * 8;
    *(half8*)(Wh + off) = h;
}

// ---------------- QKV projection: x via DMA, W DIRECT from packed layout ----
// 512 blocks x 512 thr (8 waves). Block = 32 rows, 12 ctiles; wave: strip=(w&1),
// grp=(w>>1) -> 3 ctiles. x staged by DMA (1 dma16/wave/chunk, 2x8KB dbuf,
// swizzled). W ping-pong prefetched into named wA/wB register sets one chunk
// ahead from the PACKED layout -> each half8 = 4x256B contiguous (coalesced),
// and the DMA path carries only x (64MB) instead of 260MB.
__global__ __launch_bounds__(512) void qkv_kernel(
    const float* __restrict__ x, const _Float16* __restrict__ Wh,
    _Float16* __restrict__ qh, _Float16* __restrict__ kh, _Float16* __restrict__ vpt)
{
    __shared__ __align__(16) char arena[16384];  // x: 2 x 8KB
    const int t = threadIdx.x, lane = t & 63, wave = t >> 6;
    const int l15 = lane & 15, quad = lane >> 4;
    const int strip = wave & 1, grp = wave >> 1;   // grp in [0,4)
    const int row0 = blockIdx.x * 32;

    auto issueX = [&](int buf, int k0) {
        // 8 instrs total (1/wave): 4 rows x 16 swizzled 16B segs each
        const int row = wave * 4 + (lane >> 4);
        const int logi = (lane & 15) ^ (row & 15);
        dma16((float*)(arena + buf * 8192) + wave * 256,
              x + (size_t)(row0 + row) * EMB + k0 + logi * 4);
    };
    auto loadW = [&](int k0, half8 (&w)[3][2]) {
        const int kchunk = k0 >> 6;
        #pragma unroll
        for (int j = 0; j < 3; ++j) {
            const int tile = grp * 3 + j;
            const _Float16* wp = Wh
                + (((size_t)tile * 16 + kchunk) * 8) * 128;   // seg-major base
            w[j][0] = *(const half8*)(wp + ((quad    ) * 16 + l15) * 8);
            w[j][1] = *(const half8*)(wp + ((4 + quad) * 16 + l15) * 8);
        }
    };

    f32x4 acc[3] = {};
    const int xrow = strip * 16 + l15;
    auto step = [&](int buf, const half8 (&w)[3][2]) {
        const float* xb = (const float*)(arena + buf * 8192);
        half8 a[2];
        #pragma unroll
        for (int kc = 0; kc < 2; ++kc) {
            const int s0 = kc * 8 + quad * 2;
            f32x4 u0 = *(const f32x4*)(xb + xrow * 64 + ((s0    ) ^ l15) * 4);
            f32x4 u1 = *(const f32x4*)(xb + xrow * 64 + ((s0 + 1) ^ l15) * 4);
            a[kc][0] = (_Float16)u0[0]; a[kc][1] = (_Float16)u0[1];
            a[kc][2] = (_Float16)u0[2]; a[kc][3] = (_Float16)u0[3];
            a[kc][4] = (_Float16)u1[0]; a[kc][5] = (_Float16)u1[1];
            a[kc][6] = (_Float16)u1[2]; a[kc][7] = (_Float16)u1[3];
        }
        #pragma unroll
        for (int j = 0; j < 3; ++j) {
            acc[j] = __builtin_amdgcn_mfma_f32_16x16x32_f16(a[0], w[j][0], acc[j], 0, 0, 0);
            acc[j] = __builtin_amdgcn_mfma_f32_16x16x32_f16(a[1], w[j][1], acc[j], 0, 0, 0);
        }
    };

    half8 wA[3][2], wB[3][2];
    issueX(0, 0);
    loadW(0, wA);
    __syncthreads();
    for (int it = 0; it < 16; it += 2) {
        issueX(1, (it + 1) * 64);            // it+1 <= 15 always
        loadW((it + 1) * 64, wB);
        step(0, wA);
        __syncthreads();
        if (it + 2 < 16) { issueX(0, (it + 2) * 64); loadW((it + 2) * 64, wA); }
        step(1, wB);
        __syncthreads();
    }

    #pragma unroll
    for (int j = 0; j < 3; ++j) {
        const int c = grp * 3 + j, m = c >> 2, n = c & 3;
        if (m < 2) {
            _Float16* __restrict__ dst = (m == 0) ? qh : kh;
            #pragma unroll
            for (int r = 0; r < 4; ++r)
                dst[(size_t)(row0 + strip * 16 + quad * 4 + r) * HD + n * 16 + l15] =
                    (_Float16)acc[j][r];
        } else {
            const int rg = row0 + strip * 16 + quad * 4;
            const int b = rg >> 11, s = rg & 2047;
            half4 h;
            h[0] = (_Float16)acc[j][0]; h[1] = (_Float16)acc[j][1];
            h[2] = (_Float16)acc[j][2]; h[3] = (_Float16)acc[j][3];
            *(half4*)(vpt + ((size_t)b * HD + n * 16 + l15) * SEQ + s) = h;
        }
    }
}

// ---------------- Column-softmax partials (r7-proven, 64-key blocks) --------
// grid (32,8,2) x 256 thr (4 waves). Block = 64 keys (ka[4][2] A-frags in
// regs); z = query-half: 16 DMA'd chunks of 64 queries, double-buffered,
// swizzled; wave w -> queries w*16 of each chunk. Writes RAW partial sums.
__global__ __launch_bounds__(256) void stats_kernel(
    const _Float16* __restrict__ qh, const _Float16* __restrict__ kh,
    float* __restrict__ l_part)
{
    __shared__ __align__(16) char arena[16384];  // q: 2x8KB
    __shared__ float red[4][64];
    const int t = threadIdx.x, lane = t & 63, wave = t >> 6;
    const int l15 = lane & 15, quad = lane >> 4;
    const int b = blockIdx.y, c0 = blockIdx.x * 64, z = blockIdx.z;
    const int qbase = z * 1024;

    half8 ka[4][2];
    #pragma unroll
    for (int kt = 0; kt < 4; ++kt) {
        const _Float16* kp = kh + ((size_t)b * SEQ + c0 + kt * 16 + l15) * HD + quad * 8;
        ka[kt][0] = *(const half8*)(kp);
        ka[kt][1] = *(const half8*)(kp + 32);
    }

    auto issue = [&](int buf, int q0) {
        #pragma unroll
        for (int jj = 0; jj < 2; ++jj) {
            const int j = wave * 2 + jj;
            const int qq = j * 8 + (lane >> 3);
            const int logi = (lane & 7) ^ (qq & 7);
            dma16((_Float16*)(arena + buf * 8192) + j * 512,
                  qh + ((size_t)b * SEQ + q0 + qq) * HD + logi * 8);
        }
    };

    issue(0, qbase);
    __syncthreads();

    float csum[4][4] = {};
    const int qrow = wave * 16 + l15;
    for (int it = 0; it < 16; ++it) {
        const int buf = it & 1;
        if (it + 1 < 16) issue(buf ^ 1, qbase + (it + 1) * 64);
        const _Float16* qb = (const _Float16*)(arena + buf * 8192);
        half8 bq0 = *(const half8*)(qb + qrow * 64 + (((quad    ) ^ (l15 & 7)) * 8));
        half8 bq1 = *(const half8*)(qb + qrow * 64 + (((4 + quad) ^ (l15 & 7)) * 8));
        #pragma unroll
        for (int kt = 0; kt < 4; ++kt) {
            f32x4 s = {};
            s = __builtin_amdgcn_mfma_f32_16x16x32_f16(ka[kt][0], bq0, s, 0, 0, 0);
            s = __builtin_amdgcn_mfma_f32_16x16x32_f16(ka[kt][1], bq1, s, 0, 0, 0);
            #pragma unroll
            for (int r = 0; r < 4; ++r)
                csum[kt][r] += fexp2(s[r]);
        }
        __syncthreads();
    }
    #pragma unroll
    for (int kt = 0; kt < 4; ++kt)
        #pragma unroll
        for (int r = 0; r < 4; ++r) {
            csum[kt][r] += __shfl_xor(csum[kt][r], 1);
            csum[kt][r] += __shfl_xor(csum[kt][r], 2);
            csum[kt][r] += __shfl_xor(csum[kt][r], 4);
            csum[kt][r] += __shfl_xor(csum[kt][r], 8);
        }
    if (l15 == 0) {
        #pragma unroll
        for (int kt = 0; kt < 4; ++kt)
            #pragma unroll
            for (int r = 0; r < 4; ++r)
                red[wave][kt * 16 + quad * 4 + r] = csum[kt][r];
    }
    __syncthreads();
    if (t < 64)
        l_part[(size_t)z * BS + (size_t)b * SEQ + c0 + t] =
            red[0][t] + red[1][t] + red[2][t] + red[3][t];
}

// ---------------- opart[z] = P~ @ v (r7-proven, 64-row blocks) --------------
// grid (32,8,2) x 256 thr (4 waves). Block = 64 q-rows; wave w owns rows
// w*16..+15 over ALL 64 staged keys per chunk. k/v DMA'd, double-buffered,
// swizzled; l = 1/(l0+l1) in regs. Wave-private P LDS round trip (stride 76).
// Compact f32 partial write; x16 broadcast in bcast_kernel.
__global__ __launch_bounds__(256) void out_kernel(
    const _Float16* __restrict__ qh, const _Float16* __restrict__ kh,
    const _Float16* __restrict__ vpt, const float* __restrict__ l_part,
    float* __restrict__ opart)
{
    __shared__ __align__(16) char arena[42496];
    // [0,16384)      kbuf [2][64][64] fp16
    // [16384,32768)  vbuf [2][64][64] fp16
    // [32768,42496)  ps   [4 waves][16][76] fp16
    const int t = threadIdx.x, lane = t & 63, wave = t >> 6;
    const int l15 = lane & 15, quad = lane >> 4;
    const int b = blockIdx.y, r0 = blockIdx.x * 64, z = blockIdx.z;
    const int kbase = z * 1024;

    half8 aq[2];
    {
        const _Float16* qp = qh + ((size_t)b * SEQ + r0 + wave * 16 + l15) * HD + quad * 8;
        aq[0] = *(const half8*)(qp);
        aq[1] = *(const half8*)(qp + 32);
    }

    auto issue = [&](int buf, int c0) {
        #pragma unroll
        for (int jj = 0; jj < 4; ++jj) {
            if (wave < 2) {        // k: 8 instrs, 64 key-rows x 64B
                const int j = wave * 4 + jj;
                const int key = j * 8 + (lane >> 3);
                const int logi = (lane & 7) ^ (key & 7);
                dma16((_Float16*)(arena + buf * 8192) + j * 512,
                      kh + ((size_t)b * SEQ + c0 + key) * HD + logi * 8);
            } else {               // v: 8 instrs (vpt is [b][d][s])
                const int j = (wave - 2) * 4 + jj;
                const int d = j * 8 + (lane >> 3);
                const int logi = (lane & 7) ^ (d & 7);
                dma16((_Float16*)(arena + 16384 + buf * 8192) + j * 512,
                      vpt + ((size_t)b * HD + d) * SEQ + c0 + logi * 8);
            }
        }
    };

    const float* lp = l_part + (size_t)b * SEQ;   // z'=0; z'=1 at +BS

    issue(0, kbase);
    __syncthreads();

    _Float16* psb = (_Float16*)(arena + 32768) + wave * 1216;  // [16][76]
    f32x4 oacc[4] = {};
    for (int it = 0; it < 16; ++it) {
        const int buf = it & 1;
        if (it + 1 < 16) issue(buf ^ 1, kbase + (it + 1) * 64);
        const _Float16* kb = (const _Float16*)(arena + buf * 8192);
        const _Float16* vb = (const _Float16*)(arena + 16384 + buf * 8192);

        #pragma unroll
        for (int ct = 0; ct < 4; ++ct) {
            const int key = ct * 16 + l15;
            f32x4 s = {};
            half8 kf0 = *(const half8*)(kb + key * 64 + (((quad    ) ^ (l15 & 7)) * 8));
            half8 kf1 = *(const half8*)(kb + key * 64 + (((4 + quad) ^ (l15 & 7)) * 8));
            s = __builtin_amdgcn_mfma_f32_16x16x32_f16(aq[0], kf0, s, 0, 0, 0);
            s = __builtin_amdgcn_mfma_f32_16x16x32_f16(aq[1], kf1, s, 0, 0, 0);
            const int kg = kbase + it * 64 + key;
            const float li = frcp(lp[kg] + lp[BS + kg]);
            #pragma unroll
            for (int r = 0; r < 4; ++r)
                psb[(quad * 4 + r) * 76 + ct * 16 + l15] =
                    (_Float16)(fexp2(s[r]) * li);
        }
        half8 paA = *(const half8*)(psb + l15 * 76 + quad * 8);        // keys 0..31
        half8 paB = *(const half8*)(psb + l15 * 76 + 32 + quad * 8);   // keys 32..63
        #pragma unroll
        for (int n = 0; n < 4; ++n) {
            const int d = n * 16 + l15;
            half8 vfA = *(const half8*)(vb + d * 64 + (((quad    ) ^ (l15 & 7)) * 8));
            half8 vfB = *(const half8*)(vb + d * 64 + (((4 + quad) ^ (l15 & 7)) * 8));
            oacc[n] = __builtin_amdgcn_mfma_f32_16x16x32_f16(paA, vfA, oacc[n], 0, 0, 0);
            oacc[n] = __builtin_amdgcn_mfma_f32_16x16x32_f16(paB, vfB, oacc[n], 0, 0, 0);
        }
        __syncthreads();
    }

    // compact write: wave-private 16x64 f32 tile -> opart[z]
    #pragma unroll
    for (int n = 0; n < 4; ++n)
        #pragma unroll
        for (int r = 0; r < 4; ++r) {
            const int row = r0 + wave * 16 + quad * 4 + r;
            opart[(size_t)z * ((size_t)BS * HD)
                  + ((size_t)b * SEQ + row) * HD + n * 16 + l15] = oacc[n][r];
        }
}

// ---------------- out[b,s,h*64+d] = opart[0][b,s,d] + opart[1][b,s,d] -----
// Pure-BW broadcast: one block per (b,s) row; 256 threads cover the 1024-f32
// output row with one float4 each. Reads 8 MiB, writes 64 MiB, coalesced.
__global__ __launch_bounds__(256) void bcast_kernel(
    const float* __restrict__ opart, float* __restrict__ out)
{
    const int row = blockIdx.x;          // [0, BS)
    const int t = threadIdx.x;
    const int d = (t * 4) & 63;          // source offset within the 64-f32 O row
    const float* o0 = opart + (size_t)row * HD + d;
    const float* o1 = o0 + (size_t)BS * HD;
    float4 a = *(const float4*)o0;
    float4 c = *(const float4*)o1;
    float4 s;
    s.x = a.x + c.x; s.y = a.y + c.y; s.z = a.z + c.z; s.w = a.w + c.w;
    *(float4*)(out + (size_t)row * (HD * HEADS) + t * 4) = s;
}

extern "C" void kernel_launch(void* const* d_in, const int* in_sizes, int n_in,
                              void* d_out, int out_size, void* d_ws, size_t ws_size,
                              hipStream_t stream)
{
    const float* x  = (const float*)d_in[0];
    const float* Wq = (const float*)d_in[1];
    const float* Wk = (const float*)d_in[2];
    const float* Wv = (const float*)d_in[3];
    float* out = (float*)d_out;

    const size_t N = (size_t)BATCH * SEQ * HD;   // 1,048,576
    _Float16* qh  = (_Float16*)d_ws;
    _Float16* kh  = qh + N;
    _Float16* vpt = kh + N;
    _Float16* Wh  = vpt + N;                     // 3*64*1024 halves (packed)
    float* l_part = (float*)(Wh + 196608);       // [2][B][S] f32 (128 KB)
    float* opart  = l_part + 2 * BS;             // [2][B][S][64] f32 (8 MiB)

    wcvt_kernel <<<dim3(32, 3),    256, 0, stream>>>(Wq, Wk, Wv, Wh);
    qkv_kernel  <<<dim3(512),      512, 0, stream>>>(x, Wh, qh, kh, vpt);
    stats_kernel<<<dim3(32, 8, 2), 256, 0, stream>>>(qh, kh, l_part);
    out_kernel  <<<dim3(32, 8, 2), 256, 0, stream>>>(qh, kh, vpt, l_part, opart);
    bcast_kernel<<<dim3(BS),       256, 0, stream>>>(opart, out);
}